// Round 4
// baseline (285.933 us; speedup 1.0000x reference)
//
#include <hip/hip_runtime.h>
#include <hip/hip_bf16.h>

#define HID 128
#define TE  64     // edges per block
#define CPB 4      // cells per edge-block
#define CAP 16     // edges per cell (E/G)

// wt region offsets (bf16 elements): Wt[n][k] transposed weights
#define WT_E1 0        // [128][32]  (ew1 K-padded 6->32)
#define WT_E2 4096     // [128][128]
#define WT_M1 20480    // [128][256]
#define WT_M2 53248    // [128][128]
#define WT_U1 69632    // [128][128]
#define WT_U2 86016    // [128][128]
#define WT_TOTAL 102400

typedef __attribute__((ext_vector_type(8))) short bf16x8;
typedef __attribute__((ext_vector_type(4))) float f32x4;

#define MFMA(a, b, c) __builtin_amdgcn_mfma_f32_16x16x32_bf16(a, b, c, 0, 0, 0)

__device__ __forceinline__ float silu_f(float x) {
    return x * (1.0f / (1.0f + __expf(-x)));
}

__device__ __forceinline__ short f2b(float x) {
    __hip_bfloat16 h = __float2bfloat16(x);   // RNE
    return *(short*)&h;
}

__device__ __forceinline__ float b2f(unsigned short u) {
    union { unsigned u32; float f; } v;
    v.u32 = ((unsigned)u) << 16;
    return v.f;
}

// Swizzled LDS pointer for 64x128 bf16 act buffers (256B rows).
// byte ^= ((row>>1)&7)<<4 : keeps 16B alignment; makes both the b128
// k-reads and the scalar column-writes <=2-way bank conflicts.
__device__ __forceinline__ void* ldsp(void* base, int row, int col /*shorts*/) {
    int byte = (row << 8) + (col << 1);
    byte ^= ((row >> 1) & 7) << 4;
    return (char*)base + byte;
}

__device__ __forceinline__ void zero_acc(f32x4 acc[4][2]) {
    #pragma unroll
    for (int m = 0; m < 4; ++m) {
        acc[m][0] = (f32x4)(0.0f);
        acc[m][1] = (f32x4)(0.0f);
    }
}

// acc += A(64 rows from swizzled LDS) @ Wt(cols nb..nb+31, k offset kB0)
__device__ __forceinline__ void gemm_swz(f32x4 acc[4][2], const short* sA,
                                         const short* __restrict__ wtB, int ldb, int kB0,
                                         int ksteps, int q, int h, int nb)
{
    for (int ks = 0; ks < ksteps; ++ks) {
        int kb = kB0 + ks * 32 + h * 8;
        bf16x8 b0 = *(const bf16x8*)(wtB + (size_t)(nb + q) * ldb + kb);
        bf16x8 b1 = *(const bf16x8*)(wtB + (size_t)(nb + 16 + q) * ldb + kb);
        int ka = ks * 32 + h * 8;
        #pragma unroll
        for (int m = 0; m < 4; ++m) {
            bf16x8 a = *(const bf16x8*)ldsp((void*)sA, m * 16 + q, ka);
            acc[m][0] = MFMA(a, b0, acc[m][0]);
            acc[m][1] = MFMA(a, b1, acc[m][1]);
        }
    }
}

// bias + (optional silu) -> bf16 -> swizzled LDS
__device__ __forceinline__ void epi_swz(f32x4 acc[4][2], const float* __restrict__ bias,
                                        short* sOut, int q, int h, int nb, bool act)
{
    #pragma unroll
    for (int nf = 0; nf < 2; ++nf) {
        int n = nb + nf * 16 + q;
        float bb = bias[n];
        #pragma unroll
        for (int m = 0; m < 4; ++m) {
            #pragma unroll
            for (int r = 0; r < 4; ++r) {
                float z = acc[m][nf][r] + bb;
                if (act) z = silu_f(z);
                *(short*)ldsp(sOut, m * 16 + h * 4 + r, n) = f2b(z);
            }
        }
    }
}

// ---------------------------------------------------------------------------
// prep0: edge binning (blocks 0..nbin-1) + weight conversion (rest)
// ---------------------------------------------------------------------------
extern "C" __global__ void __launch_bounds__(256)
prep0(const int* __restrict__ ei, int* __restrict__ cnt, int* __restrict__ bin, int E,
      const float* __restrict__ ew1, const float* __restrict__ ew2,
      const float* __restrict__ mw1, const float* __restrict__ mw2,
      const float* __restrict__ uw1, const float* __restrict__ uw2,
      short* __restrict__ wt)
{
    int nbin = (E + 255) / 256;
    if ((int)blockIdx.x < nbin) {
        int e = blockIdx.x * 256 + threadIdx.x;
        if (e < E) {
            int j = ei[E + e];
            int slot = atomicAdd(&cnt[j], 1);
            if (slot < CAP) bin[(size_t)j * CAP + slot] = e;
        }
        return;
    }
    int idx = (blockIdx.x - nbin) * 256 + threadIdx.x;
    if (idx >= WT_TOTAL) return;
    int r = idx;
    if (r < 4096) { int n = r >> 5, k = r & 31; wt[idx] = f2b(k < 6 ? ew1[k * HID + n] : 0.0f); return; }
    r -= 4096;
    if (r < 16384) { int n = r >> 7, k = r & 127; wt[idx] = f2b(ew2[k * HID + n]); return; }
    r -= 16384;
    if (r < 32768) { int n = r >> 8, k = r & 255; wt[idx] = f2b(mw1[k * HID + n]); return; }
    r -= 32768;
    if (r < 16384) { int n = r >> 7, k = r & 127; wt[idx] = f2b(mw2[k * HID + n]); return; }
    r -= 16384;
    if (r < 16384) { int n = r >> 7, k = r & 127; wt[idx] = f2b(uw1[k * HID + n]); return; }
    r -= 16384;
    { int n = r >> 7, k = r & 127; wt[idx] = f2b(uw2[k * HID + n]); return; }
}

// ---------------------------------------------------------------------------
// prep_gemm: pre[node] = emb[node] @ mw1[:128] + mb1   (bf16 out)
// Hoists the per-edge emb GEMM to per-node (8x FLOP reduction).
// ---------------------------------------------------------------------------
extern "C" __global__ void __launch_bounds__(256, 4)
prep_gemm(const float* __restrict__ emb, const float* __restrict__ mb1,
          const short* __restrict__ wt, unsigned short* __restrict__ pre)
{
    __shared__ short s_x[TE * HID];
    const int t  = threadIdx.x;
    const int r0 = blockIdx.x * TE;

    {   // stage 64 fp32 rows -> bf16 swizzled LDS
        int row = t >> 2, part = t & 3;
        const float4* src = (const float4*)(emb + (size_t)(r0 + row) * HID + part * 32);
        #pragma unroll
        for (int c = 0; c < 4; ++c) {
            float4 v0 = src[c * 2], v1 = src[c * 2 + 1];
            union { unsigned u[4]; uint4 q4; } p;
            p.u[0] = (unsigned)(unsigned short)f2b(v0.x) | ((unsigned)(unsigned short)f2b(v0.y) << 16);
            p.u[1] = (unsigned)(unsigned short)f2b(v0.z) | ((unsigned)(unsigned short)f2b(v0.w) << 16);
            p.u[2] = (unsigned)(unsigned short)f2b(v1.x) | ((unsigned)(unsigned short)f2b(v1.y) << 16);
            p.u[3] = (unsigned)(unsigned short)f2b(v1.z) | ((unsigned)(unsigned short)f2b(v1.w) << 16);
            *(uint4*)ldsp(s_x, row, part * 32 + c * 8) = p.q4;
        }
    }
    __syncthreads();

    const int lane = t & 63, q = lane & 15, h = lane >> 4, nb = (t >> 6) * 32;
    f32x4 acc[4][2];
    zero_acc(acc);
    gemm_swz(acc, s_x, wt + WT_M1, 256, 0, 4, q, h, nb);

    #pragma unroll
    for (int nf = 0; nf < 2; ++nf) {
        int n = nb + nf * 16 + q;
        float bb = mb1[n];
        #pragma unroll
        for (int m = 0; m < 4; ++m)
            #pragma unroll
            for (int r = 0; r < 4; ++r)
                pre[(size_t)(r0 + m * 16 + h * 4 + r) * HID + n] =
                    (unsigned short)f2b(acc[m][nf][r] + bb);
    }
}

// ---------------------------------------------------------------------------
// edge kernel: 4 cells x 16 binned edges; full edge MLP + mean + fused
// update MLP. One kernel writes the final output for its 4 cells.
// ---------------------------------------------------------------------------
extern "C" __global__ void __launch_bounds__(256, 4)
edge_kernel(const float* __restrict__ npos,
            const float* __restrict__ gpos,
            const int* __restrict__ ei,
            const float* __restrict__ eb1, const float* __restrict__ eb2,
            const float* __restrict__ mb2,
            const float* __restrict__ ub1, const float* __restrict__ ub2,
            const short* __restrict__ wt,
            const int* __restrict__ cnt,
            const int* __restrict__ bin,
            const unsigned short* __restrict__ pre,
            float* __restrict__ out,
            int E)
{
    __shared__ short s_a[TE * 40];    // attr rows; later overlaid by s_mean[16][136]
    __shared__ short s_x[TE * HID];   // swizzled act ping
    __shared__ short s_y[TE * HID];   // swizzled act pong
    __shared__ int   s_ii[TE];

    const int t  = threadIdx.x;
    const int c0 = blockIdx.x * CPB;

    // ---- stage: attr rows + node ids
    if (t < TE) {
        int cell = c0 + (t >> 4);
        int eid  = bin[(size_t)c0 * CAP + t];
        int i    = ei[eid];
        s_ii[t] = i;
        const float* np = npos + (size_t)i * 3;
        const float* gp = gpos + (size_t)cell * 3;
        short* arow = s_a + t * 40;
        arow[0] = f2b(np[0]); arow[1] = f2b(np[1]); arow[2] = f2b(np[2]);
        arow[3] = f2b(gp[0]); arow[4] = f2b(gp[1]); arow[5] = f2b(gp[2]);
        #pragma unroll
        for (int k = 6; k < 32; ++k) arow[k] = 0;
    }
    float inv[CPB];
    #pragma unroll
    for (int m = 0; m < CPB; ++m) {
        int c = cnt[c0 + m];
        inv[m] = 1.0f / (float)(c > 0 ? c : 1);
    }
    __syncthreads();

    const int lane = t & 63, q = lane & 15, h = lane >> 4, nb = (t >> 6) * 32;
    f32x4 acc[4][2];

    // ---- L1: h1 = silu(attr @ ew1 + eb1) -> s_x  (K=32 padded)
    zero_acc(acc);
    {
        int kb = h * 8;
        bf16x8 b0 = *(const bf16x8*)(wt + WT_E1 + (nb + q) * 32 + kb);
        bf16x8 b1 = *(const bf16x8*)(wt + WT_E1 + (nb + 16 + q) * 32 + kb);
        #pragma unroll
        for (int m = 0; m < 4; ++m) {
            bf16x8 a = *(const bf16x8*)(s_a + (m * 16 + q) * 40 + kb);
            acc[m][0] = MFMA(a, b0, acc[m][0]);
            acc[m][1] = MFMA(a, b1, acc[m][1]);
        }
    }
    epi_swz(acc, eb1, s_x, q, h, nb, true);
    __syncthreads();

    // ---- L2: pos = h1 @ ew2 + eb2 -> s_y
    zero_acc(acc);
    gemm_swz(acc, s_x, wt + WT_E2, 128, 0, 4, q, h, nb);
    epi_swz(acc, eb2, s_y, q, h, nb, false);
    __syncthreads();

    // ---- L3: h2 = silu(pos @ mw1[128:] + pre[i]) -> s_x  (pre has emb-part + mb1)
    zero_acc(acc);
    gemm_swz(acc, s_y, wt + WT_M1, 256, 128, 4, q, h, nb);
    #pragma unroll
    for (int m = 0; m < 4; ++m) {
        #pragma unroll
        for (int r = 0; r < 4; ++r) {
            int row = m * 16 + h * 4 + r;
            const unsigned short* prow = pre + (size_t)s_ii[row] * HID;
            #pragma unroll
            for (int nf = 0; nf < 2; ++nf) {
                int n = nb + nf * 16 + q;
                float z = silu_f(acc[m][nf][r] + b2f(prow[n]));
                *(short*)ldsp(s_x, row, n) = f2b(z);
            }
        }
    }
    __syncthreads();

    // ---- L4: message = h2 @ mw2; per-cell mean -> s_mean (overlays s_a)
    zero_acc(acc);
    gemm_swz(acc, s_x, wt + WT_M2, 128, 0, 4, q, h, nb);

    short* s_mean = s_a;   // [16][136], rows 0..3 real, 4..15 zero
    #pragma unroll
    for (int m = 0; m < CPB; ++m) {
        #pragma unroll
        for (int nf = 0; nf < 2; ++nf) {
            f32x4 v = acc[m][nf];
            float s = (v[0] + v[1]) + (v[2] + v[3]);
            s += __shfl_xor(s, 16);
            s += __shfl_xor(s, 32);
            if (h == 0) {
                int n = nb + nf * 16 + q;
                s_mean[m * 136 + n] = f2b(s * inv[m] + mb2[n]);
            }
        }
    }
    for (int z = t; z < 12 * 136; z += 256) s_mean[4 * 136 + z] = 0;
    __syncthreads();

    // ---- u1: silu(mean @ uw1 + ub1) -> s_y rows 0..15 (pad rows finite)
    f32x4 a2[2];
    a2[0] = (f32x4)(0.0f); a2[1] = (f32x4)(0.0f);
    #pragma unroll
    for (int ks = 0; ks < 4; ++ks) {
        int kb = ks * 32 + h * 8;
        bf16x8 b0 = *(const bf16x8*)(wt + WT_U1 + (nb + q) * 128 + kb);
        bf16x8 b1 = *(const bf16x8*)(wt + WT_U1 + (nb + 16 + q) * 128 + kb);
        bf16x8 a = *(const bf16x8*)(s_mean + q * 136 + kb);
        a2[0] = MFMA(a, b0, a2[0]);
        a2[1] = MFMA(a, b1, a2[1]);
    }
    #pragma unroll
    for (int nf = 0; nf < 2; ++nf) {
        int n = nb + nf * 16 + q;
        float bb = ub1[n];
        #pragma unroll
        for (int r = 0; r < 4; ++r)
            *(short*)ldsp(s_y, h * 4 + r, n) = f2b(silu_f(a2[nf][r] + bb));
    }
    __syncthreads();

    // ---- u2: out = h @ uw2 + ub2  (rows 0..3 = cells)
    a2[0] = (f32x4)(0.0f); a2[1] = (f32x4)(0.0f);
    #pragma unroll
    for (int ks = 0; ks < 4; ++ks) {
        int kb = ks * 32 + h * 8;
        bf16x8 b0 = *(const bf16x8*)(wt + WT_U2 + (nb + q) * 128 + kb);
        bf16x8 b1 = *(const bf16x8*)(wt + WT_U2 + (nb + 16 + q) * 128 + kb);
        bf16x8 a = *(const bf16x8*)ldsp(s_y, q, kb - 0 * 32);   // rows 0..15
        a2[0] = MFMA(a, b0, a2[0]);
        a2[1] = MFMA(a, b1, a2[1]);
    }
    if (h == 0) {
        #pragma unroll
        for (int nf = 0; nf < 2; ++nf) {
            int n = nb + nf * 16 + q;
            float bb = ub2[n];
            #pragma unroll
            for (int r = 0; r < 4; ++r)
                out[(size_t)(c0 + r) * HID + n] = a2[nf][r] + bb;
        }
    }
}

// ---------------------------------------------------------------------------
extern "C" void kernel_launch(void* const* d_in, const int* in_sizes, int n_in,
                              void* d_out, int out_size, void* d_ws, size_t ws_size,
                              hipStream_t stream)
{
    const float* emb  = (const float*)d_in[0];
    const float* npos = (const float*)d_in[1];
    const float* gpos = (const float*)d_in[2];
    const int*   ei   = (const int*)d_in[3];
    const float* ew1  = (const float*)d_in[4];
    const float* eb1  = (const float*)d_in[5];
    const float* ew2  = (const float*)d_in[6];
    const float* eb2  = (const float*)d_in[7];
    const float* mw1  = (const float*)d_in[8];
    const float* mb1  = (const float*)d_in[9];
    const float* mw2  = (const float*)d_in[10];
    const float* mb2  = (const float*)d_in[11];
    const float* uw1  = (const float*)d_in[12];
    const float* ub1  = (const float*)d_in[13];
    const float* uw2  = (const float*)d_in[14];
    const float* ub2  = (const float*)d_in[15];

    const int E  = in_sizes[3] / 2;
    const int G  = in_sizes[2] / 3;
    const int NN = in_sizes[0] / HID;

    // ws layout: pre bf16[NN*HID] | cnt int[G] | bin int[G*CAP] | wt bf16[WT_TOTAL]
    unsigned short* pre = (unsigned short*)d_ws;
    char* p = (char*)d_ws + (size_t)NN * HID * 2;
    int*   cnt = (int*)p;                 p += (size_t)G * 4;
    int*   bin = (int*)p;                 p += (size_t)G * CAP * 4;
    short* wt  = (short*)p;

    hipMemsetAsync(cnt, 0, (size_t)G * 4, stream);

    int nbin = (E + 255) / 256;
    int ncvt = (WT_TOTAL + 255) / 256;
    prep0<<<nbin + ncvt, 256, 0, stream>>>(ei, cnt, bin, E, ew1, ew2, mw1, mw2, uw1, uw2, wt);
    prep_gemm<<<NN / TE, 256, 0, stream>>>(emb, mb1, wt, pre);
    edge_kernel<<<G / CPB, 256, 0, stream>>>(npos, gpos, ei,
                                             eb1, eb2, mb2, ub1, ub2,
                                             wt, cnt, bin, pre, (float*)d_out, E);
}

// Round 5
// 260.285 us; speedup vs baseline: 1.0985x; 1.0985x over previous
//
#include <hip/hip_runtime.h>
#include <hip/hip_bf16.h>

#define HID 128
#define TE  64     // edges per block
#define CPB 4      // cells per edge-block
#define CAP 16     // edges per cell (E/G)

// wt region offsets (bf16 elements): Wt[n][k] transposed weights
#define WT_E1 0        // [128][32]  (ew1 K-padded 6->32)
#define WT_E2 4096     // [128][128]
#define WT_M1 20480    // [128][256]
#define WT_M2 53248    // [128][128]
#define WT_U1 69632    // [128][128]
#define WT_U2 86016    // [128][128]
#define WT_TOTAL 102400

typedef __attribute__((ext_vector_type(8))) short bf16x8;
typedef __attribute__((ext_vector_type(4))) float f32x4;

#define MFMA(a, b, c) __builtin_amdgcn_mfma_f32_16x16x32_bf16(a, b, c, 0, 0, 0)

__device__ __forceinline__ float silu_f(float x) {
    return x * (1.0f / (1.0f + __expf(-x)));
}

__device__ __forceinline__ short f2b(float x) {
    __hip_bfloat16 h = __float2bfloat16(x);   // RNE
    return *(short*)&h;
}

__device__ __forceinline__ float b2f(unsigned short u) {
    union { unsigned u32; float f; } v;
    v.u32 = ((unsigned)u) << 16;
    return v.f;
}

// Swizzled LDS address for 64x128 bf16 act buffers (256B rows).
// byte ^= (row&7)<<4 : 16B-granule XOR; preserves 8B/16B alignment.
// Makes b128 k-reads AND short4 feature-writes bank-uniform.
__device__ __forceinline__ void* ldsp(void* base, int row, int col /*shorts*/) {
    int byte = (row << 8) + (col << 1);
    byte ^= (row & 7) << 4;
    return (char*)base + byte;
}

__device__ __forceinline__ void zero_acc(f32x4 acc[4][2]) {
    #pragma unroll
    for (int m = 0; m < 4; ++m) {
        acc[m][0] = (f32x4)(0.0f);
        acc[m][1] = (f32x4)(0.0f);
    }
}

// ---- orientation A: act rows in C (acc[m][nf]: row=edge m*16+h*4+r, col=feat)
__device__ __forceinline__ void gemm_actA(f32x4 acc[4][2], const short* sA,
                                          const short* __restrict__ wtB, int ldb, int kB0,
                                          int ksteps, int q, int h, int nb)
{
    for (int ks = 0; ks < ksteps; ++ks) {
        int kb = kB0 + ks * 32 + h * 8;
        bf16x8 b0 = *(const bf16x8*)(wtB + (size_t)(nb + q) * ldb + kb);
        bf16x8 b1 = *(const bf16x8*)(wtB + (size_t)(nb + 16 + q) * ldb + kb);
        int ka = ks * 32 + h * 8;
        #pragma unroll
        for (int m = 0; m < 4; ++m) {
            bf16x8 a = *(const bf16x8*)ldsp((void*)sA, m * 16 + q, ka);
            acc[m][0] = MFMA(a, b0, acc[m][0]);
            acc[m][1] = MFMA(a, b1, acc[m][1]);
        }
    }
}

// ---- orientation B (swapped): weights in A, act in B.
// acc[e4][nf]: C row = feature nb+nf*16+h*4+r, C col = edge e4*16+q.
__device__ __forceinline__ void gemm_swap(f32x4 acc[4][2], const short* sAct,
                                          const short* __restrict__ wtA, int lda, int kW0,
                                          int ksteps, int q, int h, int nb)
{
    for (int ks = 0; ks < ksteps; ++ks) {
        int kw = kW0 + ks * 32 + h * 8;
        bf16x8 w0 = *(const bf16x8*)(wtA + (size_t)(nb + q) * lda + kw);
        bf16x8 w1 = *(const bf16x8*)(wtA + (size_t)(nb + 16 + q) * lda + kw);
        int ka = ks * 32 + h * 8;
        #pragma unroll
        for (int e4 = 0; e4 < 4; ++e4) {
            bf16x8 b = *(const bf16x8*)ldsp((void*)sAct, e4 * 16 + q, ka);
            acc[e4][0] = MFMA(w0, b, acc[e4][0]);
            acc[e4][1] = MFMA(w1, b, acc[e4][1]);
        }
    }
}

// swapped epilogue: lane holds 4 consecutive feats of one edge -> short4 b64 write
__device__ __forceinline__ void epi_swap(f32x4 acc[4][2], const float* __restrict__ bias,
                                         short* sOut, int q, int h, int nb, bool act)
{
    #pragma unroll
    for (int nf = 0; nf < 2; ++nf) {
        int f0 = nb + nf * 16 + h * 4;
        float4 bb = *(const float4*)(bias + f0);
        #pragma unroll
        for (int e4 = 0; e4 < 4; ++e4) {
            f32x4 v = acc[e4][nf];
            float z0 = v[0] + bb.x, z1 = v[1] + bb.y;
            float z2 = v[2] + bb.z, z3 = v[3] + bb.w;
            if (act) { z0 = silu_f(z0); z1 = silu_f(z1); z2 = silu_f(z2); z3 = silu_f(z3); }
            short4 s4;
            s4.x = f2b(z0); s4.y = f2b(z1); s4.z = f2b(z2); s4.w = f2b(z3);
            *(short4*)ldsp(sOut, e4 * 16 + q, f0) = s4;
        }
    }
}

// ---------------------------------------------------------------------------
// prep0: edge binning (blocks 0..nbin-1) + weight conversion (rest)
// ---------------------------------------------------------------------------
extern "C" __global__ void __launch_bounds__(256)
prep0(const int* __restrict__ ei, int* __restrict__ cnt, int* __restrict__ bin, int E,
      const float* __restrict__ ew1, const float* __restrict__ ew2,
      const float* __restrict__ mw1, const float* __restrict__ mw2,
      const float* __restrict__ uw1, const float* __restrict__ uw2,
      short* __restrict__ wt)
{
    int nbin = (E + 255) / 256;
    if ((int)blockIdx.x < nbin) {
        int e = blockIdx.x * 256 + threadIdx.x;
        if (e < E) {
            int j = ei[E + e];
            int slot = atomicAdd(&cnt[j], 1);
            if (slot < CAP) bin[(size_t)j * CAP + slot] = e;
        }
        return;
    }
    int idx = (blockIdx.x - nbin) * 256 + threadIdx.x;
    if (idx >= WT_TOTAL) return;
    int r = idx;
    if (r < 4096) { int n = r >> 5, k = r & 31; wt[idx] = f2b(k < 6 ? ew1[k * HID + n] : 0.0f); return; }
    r -= 4096;
    if (r < 16384) { int n = r >> 7, k = r & 127; wt[idx] = f2b(ew2[k * HID + n]); return; }
    r -= 16384;
    if (r < 32768) { int n = r >> 8, k = r & 255; wt[idx] = f2b(mw1[k * HID + n]); return; }
    r -= 32768;
    if (r < 16384) { int n = r >> 7, k = r & 127; wt[idx] = f2b(mw2[k * HID + n]); return; }
    r -= 16384;
    if (r < 16384) { int n = r >> 7, k = r & 127; wt[idx] = f2b(uw1[k * HID + n]); return; }
    r -= 16384;
    { int n = r >> 7, k = r & 127; wt[idx] = f2b(uw2[k * HID + n]); return; }
}

// ---------------------------------------------------------------------------
// prep_gemm: pre[node] = emb[node] @ mw1[:128] + mb1   (bf16 out)
// ---------------------------------------------------------------------------
extern "C" __global__ void __launch_bounds__(256, 4)
prep_gemm(const float* __restrict__ emb, const float* __restrict__ mb1,
          const short* __restrict__ wt, unsigned short* __restrict__ pre)
{
    __shared__ short s_x[TE * HID];
    const int t  = threadIdx.x;
    const int r0 = blockIdx.x * TE;

    {   // stage 64 fp32 rows -> bf16 swizzled LDS
        int row = t >> 2, part = t & 3;
        const float4* src = (const float4*)(emb + (size_t)(r0 + row) * HID + part * 32);
        #pragma unroll
        for (int c = 0; c < 4; ++c) {
            float4 v0 = src[c * 2], v1 = src[c * 2 + 1];
            union { unsigned u[4]; uint4 q4; } p;
            p.u[0] = (unsigned)(unsigned short)f2b(v0.x) | ((unsigned)(unsigned short)f2b(v0.y) << 16);
            p.u[1] = (unsigned)(unsigned short)f2b(v0.z) | ((unsigned)(unsigned short)f2b(v0.w) << 16);
            p.u[2] = (unsigned)(unsigned short)f2b(v1.x) | ((unsigned)(unsigned short)f2b(v1.y) << 16);
            p.u[3] = (unsigned)(unsigned short)f2b(v1.z) | ((unsigned)(unsigned short)f2b(v1.w) << 16);
            *(uint4*)ldsp(s_x, row, part * 32 + c * 8) = p.q4;
        }
    }
    __syncthreads();

    const int lane = t & 63, q = lane & 15, h = lane >> 4, nb = (t >> 6) * 32;
    f32x4 acc[4][2];
    zero_acc(acc);
    gemm_actA(acc, s_x, wt + WT_M1, 256, 0, 4, q, h, nb);

    #pragma unroll
    for (int nf = 0; nf < 2; ++nf) {
        int n = nb + nf * 16 + q;
        float bb = mb1[n];
        #pragma unroll
        for (int m = 0; m < 4; ++m)
            #pragma unroll
            for (int r = 0; r < 4; ++r)
                pre[(size_t)(r0 + m * 16 + h * 4 + r) * HID + n] =
                    (unsigned short)f2b(acc[m][nf][r] + bb);
    }
}

// ---------------------------------------------------------------------------
// edge kernel: 4 cells x 16 binned edges; L1-L3 swapped-operand, L4 actA
// orientation for register-local mean; fused update MLP tail.
// ---------------------------------------------------------------------------
extern "C" __global__ void __launch_bounds__(256, 4)
edge_kernel(const float* __restrict__ npos,
            const float* __restrict__ gpos,
            const int* __restrict__ ei,
            const float* __restrict__ eb1, const float* __restrict__ eb2,
            const float* __restrict__ mb2,
            const float* __restrict__ ub1, const float* __restrict__ ub2,
            const short* __restrict__ wt,
            const int* __restrict__ cnt,
            const int* __restrict__ bin,
            const unsigned short* __restrict__ pre,
            float* __restrict__ out,
            int E)
{
    __shared__ short s_a[TE * 40];    // attr rows; later overlaid by s_mean[16][136]
    __shared__ short s_x[TE * HID];   // swizzled act ping
    __shared__ short s_y[TE * HID];   // swizzled act pong
    __shared__ int   s_ii[TE];

    const int t  = threadIdx.x;
    const int c0 = blockIdx.x * CPB;

    // ---- stage: attr rows + node ids
    if (t < TE) {
        int cell = c0 + (t >> 4);
        int eid  = bin[(size_t)c0 * CAP + t];
        int i    = ei[eid];
        s_ii[t] = i;
        const float* np = npos + (size_t)i * 3;
        const float* gp = gpos + (size_t)cell * 3;
        short* arow = s_a + t * 40;
        arow[0] = f2b(np[0]); arow[1] = f2b(np[1]); arow[2] = f2b(np[2]);
        arow[3] = f2b(gp[0]); arow[4] = f2b(gp[1]); arow[5] = f2b(gp[2]);
        #pragma unroll
        for (int k = 6; k < 32; ++k) arow[k] = 0;
    }
    float inv[CPB];
    #pragma unroll
    for (int m = 0; m < CPB; ++m) {
        int c = cnt[c0 + m];
        inv[m] = 1.0f / (float)(c > 0 ? c : 1);
    }
    __syncthreads();

    const int lane = t & 63, q = lane & 15, h = lane >> 4, nb = (t >> 6) * 32;

    // ---- T14: issue pre[] gather NOW (8B/lane), consume after L3's GEMM.
    uint2 pg[4][2];
    #pragma unroll
    for (int e4 = 0; e4 < 4; ++e4) {
        const unsigned short* prow = pre + (size_t)s_ii[e4 * 16 + q] * HID;
        pg[e4][0] = *(const uint2*)(prow + nb + h * 4);
        pg[e4][1] = *(const uint2*)(prow + nb + 16 + h * 4);
    }

    f32x4 acc[4][2];

    // ---- L1: h1 = silu(attr @ ew1 + eb1) -> s_x  (swapped, K=32)
    zero_acc(acc);
    {
        int kw = h * 8;
        bf16x8 w0 = *(const bf16x8*)(wt + WT_E1 + (nb + q) * 32 + kw);
        bf16x8 w1 = *(const bf16x8*)(wt + WT_E1 + (nb + 16 + q) * 32 + kw);
        #pragma unroll
        for (int e4 = 0; e4 < 4; ++e4) {
            bf16x8 b = *(const bf16x8*)(s_a + (e4 * 16 + q) * 40 + kw);
            acc[e4][0] = MFMA(w0, b, acc[e4][0]);
            acc[e4][1] = MFMA(w1, b, acc[e4][1]);
        }
    }
    epi_swap(acc, eb1, s_x, q, h, nb, true);
    __syncthreads();

    // ---- L2: pos = h1 @ ew2 + eb2 -> s_y  (swapped)
    zero_acc(acc);
    gemm_swap(acc, s_x, wt + WT_E2, 128, 0, 4, q, h, nb);
    epi_swap(acc, eb2, s_y, q, h, nb, false);
    __syncthreads();

    // ---- L3: h2 = silu(pos @ mw1[128:] + pre[i]) -> s_x  (swapped; pre has emb-part+mb1)
    zero_acc(acc);
    gemm_swap(acc, s_y, wt + WT_M1, 256, 128, 4, q, h, nb);
    #pragma unroll
    for (int e4 = 0; e4 < 4; ++e4) {
        #pragma unroll
        for (int nf = 0; nf < 2; ++nf) {
            uint2 g = pg[e4][nf];
            f32x4 v = acc[e4][nf];
            float z0 = silu_f(v[0] + b2f((unsigned short)(g.x & 0xffff)));
            float z1 = silu_f(v[1] + b2f((unsigned short)(g.x >> 16)));
            float z2 = silu_f(v[2] + b2f((unsigned short)(g.y & 0xffff)));
            float z3 = silu_f(v[3] + b2f((unsigned short)(g.y >> 16)));
            short4 s4;
            s4.x = f2b(z0); s4.y = f2b(z1); s4.z = f2b(z2); s4.w = f2b(z3);
            *(short4*)ldsp(s_x, e4 * 16 + q, nb + nf * 16 + h * 4) = s4;
        }
    }
    __syncthreads();

    // ---- L4: message = h2 @ mw2 (actA orientation); per-cell mean -> s_mean
    zero_acc(acc);
    gemm_actA(acc, s_x, wt + WT_M2, 128, 0, 4, q, h, nb);

    short* s_mean = s_a;   // [16][136], rows 0..3 real, 4..15 zero
    #pragma unroll
    for (int m = 0; m < CPB; ++m) {
        #pragma unroll
        for (int nf = 0; nf < 2; ++nf) {
            f32x4 v = acc[m][nf];
            float s = (v[0] + v[1]) + (v[2] + v[3]);
            s += __shfl_xor(s, 16);
            s += __shfl_xor(s, 32);
            if (h == 0) {
                int n = nb + nf * 16 + q;
                s_mean[m * 136 + n] = f2b(s * inv[m] + mb2[n]);
            }
        }
    }
    for (int z = t; z < 12 * 136; z += 256) s_mean[4 * 136 + z] = 0;
    __syncthreads();

    // ---- u1: silu(mean @ uw1 + ub1) -> s_y rows 0..15
    f32x4 a2[2];
    a2[0] = (f32x4)(0.0f); a2[1] = (f32x4)(0.0f);
    #pragma unroll
    for (int ks = 0; ks < 4; ++ks) {
        int kb = ks * 32 + h * 8;
        bf16x8 b0 = *(const bf16x8*)(wt + WT_U1 + (nb + q) * 128 + kb);
        bf16x8 b1 = *(const bf16x8*)(wt + WT_U1 + (nb + 16 + q) * 128 + kb);
        bf16x8 a = *(const bf16x8*)(s_mean + q * 136 + kb);
        a2[0] = MFMA(a, b0, a2[0]);
        a2[1] = MFMA(a, b1, a2[1]);
    }
    #pragma unroll
    for (int nf = 0; nf < 2; ++nf) {
        int n = nb + nf * 16 + q;
        float bb = ub1[n];
        #pragma unroll
        for (int r = 0; r < 4; ++r)
            *(short*)ldsp(s_y, h * 4 + r, n) = f2b(silu_f(a2[nf][r] + bb));
    }
    __syncthreads();

    // ---- u2: out = h @ uw2 + ub2  (rows 0..3 = cells)
    a2[0] = (f32x4)(0.0f); a2[1] = (f32x4)(0.0f);
    #pragma unroll
    for (int ks = 0; ks < 4; ++ks) {
        int kb = ks * 32 + h * 8;
        bf16x8 b0 = *(const bf16x8*)(wt + WT_U2 + (nb + q) * 128 + kb);
        bf16x8 b1 = *(const bf16x8*)(wt + WT_U2 + (nb + 16 + q) * 128 + kb);
        bf16x8 a = *(const bf16x8*)ldsp(s_y, q, kb);
        a2[0] = MFMA(a, b0, a2[0]);
        a2[1] = MFMA(a, b1, a2[1]);
    }
    if (h == 0) {
        #pragma unroll
        for (int nf = 0; nf < 2; ++nf) {
            int n = nb + nf * 16 + q;
            float bb = ub2[n];
            #pragma unroll
            for (int r = 0; r < 4; ++r)
                out[(size_t)(c0 + r) * HID + n] = a2[nf][r] + bb;
        }
    }
}

// ---------------------------------------------------------------------------
extern "C" void kernel_launch(void* const* d_in, const int* in_sizes, int n_in,
                              void* d_out, int out_size, void* d_ws, size_t ws_size,
                              hipStream_t stream)
{
    const float* emb  = (const float*)d_in[0];
    const float* npos = (const float*)d_in[1];
    const float* gpos = (const float*)d_in[2];
    const int*   ei   = (const int*)d_in[3];
    const float* ew1  = (const float*)d_in[4];
    const float* eb1  = (const float*)d_in[5];
    const float* ew2  = (const float*)d_in[6];
    const float* eb2  = (const float*)d_in[7];
    const float* mw1  = (const float*)d_in[8];
    const float* mb1  = (const float*)d_in[9];
    const float* mw2  = (const float*)d_in[10];
    const float* mb2  = (const float*)d_in[11];
    const float* uw1  = (const float*)d_in[12];
    const float* ub1  = (const float*)d_in[13];
    const float* uw2  = (const float*)d_in[14];
    const float* ub2  = (const float*)d_in[15];

    const int E  = in_sizes[3] / 2;
    const int G  = in_sizes[2] / 3;
    const int NN = in_sizes[0] / HID;

    // ws layout: pre bf16[NN*HID] | cnt int[G] | bin int[G*CAP] | wt bf16[WT_TOTAL]
    unsigned short* pre = (unsigned short*)d_ws;
    char* p = (char*)d_ws + (size_t)NN * HID * 2;
    int*   cnt = (int*)p;                 p += (size_t)G * 4;
    int*   bin = (int*)p;                 p += (size_t)G * CAP * 4;
    short* wt  = (short*)p;

    hipMemsetAsync(cnt, 0, (size_t)G * (4 + CAP * 4), stream);   // cnt + bin

    int nbin = (E + 255) / 256;
    int ncvt = (WT_TOTAL + 255) / 256;
    prep0<<<nbin + ncvt, 256, 0, stream>>>(ei, cnt, bin, E, ew1, ew2, mw1, mw2, uw1, uw2, wt);
    prep_gemm<<<NN / TE, 256, 0, stream>>>(emb, mb1, wt, pre);
    edge_kernel<<<G / CPB, 256, 0, stream>>>(npos, gpos, ei,
                                             eb1, eb2, mb2, ub1, ub2,
                                             wt, cnt, bin, pre, (float*)d_out, E);
}